// Round 1
// baseline (476.223 us; speedup 1.0000x reference)
//
#include <hip/hip_runtime.h>
#include <stdint.h>

typedef unsigned short u16;
typedef __bf16 bf16x8 __attribute__((ext_vector_type(8)));
typedef float f32x4 __attribute__((ext_vector_type(4)));

#define SEQ 2048
#define QKV_N 5120
#define QN 4096

__device__ __forceinline__ u16 f2bf(float f) {
  union { float f; unsigned u; } v; v.f = f;
  unsigned r = v.u + 0x7fffu + ((v.u >> 16) & 1u);
  return (u16)(r >> 16);
}

__device__ __forceinline__ void gl2lds16(const void* g, void* l) {
  __builtin_amdgcn_global_load_lds((const __attribute__((address_space(1))) void*)g,
                                   (__attribute__((address_space(3))) void*)l, 16, 0, 0);
}

// ---------------- fp32 -> bf16 convert (hidden) ----------------
__global__ __launch_bounds__(256) void k_convert(const float* __restrict__ src, u16* __restrict__ dst) {
  int i = (blockIdx.x * 256 + threadIdx.x) * 4;
  float4 v = *(const float4*)(src + i);
  ushort4 o;
  o.x = f2bf(v.x); o.y = f2bf(v.y); o.z = f2bf(v.z); o.w = f2bf(v.w);
  *(ushort4*)(dst + i) = o;
}

// ---------------- transpose + convert: src[R][C] f32 -> dst[C][R] bf16 ----------------
__global__ __launch_bounds__(256) void k_transpose(const float* __restrict__ src, u16* __restrict__ dst,
                                                   int R, int C) {
  __shared__ float t[32][33];
  int c0 = blockIdx.x * 32, r0 = blockIdx.y * 32;
  int j = threadIdx.x & 31, i0 = threadIdx.x >> 5;
#pragma unroll
  for (int p = 0; p < 4; ++p) {
    int r = i0 + p * 8;
    t[r][j] = src[(size_t)(r0 + r) * C + c0 + j];
  }
  __syncthreads();
#pragma unroll
  for (int p = 0; p < 4; ++p) {
    int r = i0 + p * 8;
    dst[(size_t)(c0 + r) * R + r0 + j] = f2bf(t[j][r]);
  }
}

// ---------------- GEMM: C[M][N] = A[M][K] (bf16) @ BT[N][K]^T (bf16), fp32 out ----------------
__global__ __launch_bounds__(256) void k_gemm_bt(const u16* __restrict__ A, const u16* __restrict__ BT,
                                                 float* __restrict__ C, int M, int N, int K) {
  __shared__ u16 As[128 * 64];
  __shared__ u16 Bs[128 * 64];
  const int tid = threadIdx.x;
  const int w = tid >> 6, lane = tid & 63, quad = lane >> 4, l15 = lane & 15;
  const int m0 = blockIdx.y * 128, n0 = blockIdx.x * 128;
  const int mw = (w & 1) * 64, nw = (w >> 1) * 64;

  f32x4 acc[4][4];
#pragma unroll
  for (int i = 0; i < 4; ++i)
#pragma unroll
    for (int j = 0; j < 4; ++j) acc[i][j] = {0.f, 0.f, 0.f, 0.f};

  const int nk = K >> 6;
  for (int kt = 0; kt < nk; ++kt) {
    const int k0 = kt << 6;
    __syncthreads();
#pragma unroll
    for (int p = 0; p < 4; ++p) {
      int ci = (w * 4 + p) * 64 + lane;
      int row = ci >> 3, pc = ci & 7, gc = pc ^ (row & 7);
      gl2lds16(A + (size_t)(m0 + row) * K + k0 + gc * 8, As + (w * 4 + p) * 512);
      gl2lds16(BT + (size_t)(n0 + row) * K + k0 + gc * 8, Bs + (w * 4 + p) * 512);
    }
    __syncthreads();
#pragma unroll
    for (int kk = 0; kk < 2; ++kk) {
      bf16x8 a[4], b[4];
#pragma unroll
      for (int mt = 0; mt < 4; ++mt) {
        int row = mw + mt * 16 + l15;
        int col = ((kk * 4 + quad) ^ (row & 7)) * 8;
        a[mt] = *(const bf16x8*)(As + row * 64 + col);
      }
#pragma unroll
      for (int nt = 0; nt < 4; ++nt) {
        int row = nw + nt * 16 + l15;
        int col = ((kk * 4 + quad) ^ (row & 7)) * 8;
        b[nt] = *(const bf16x8*)(Bs + row * 64 + col);
      }
#pragma unroll
      for (int mt = 0; mt < 4; ++mt)
#pragma unroll
        for (int nt = 0; nt < 4; ++nt)
          acc[mt][nt] = __builtin_amdgcn_mfma_f32_16x16x32_bf16(a[mt], b[nt], acc[mt][nt], 0, 0, 0);
    }
  }
#pragma unroll
  for (int mt = 0; mt < 4; ++mt)
#pragma unroll
    for (int nt = 0; nt < 4; ++nt)
#pragma unroll
      for (int r = 0; r < 4; ++r) {
        int row = m0 + mw + mt * 16 + quad * 4 + r;
        int col = n0 + nw + nt * 16 + l15;
        C[(size_t)row * N + col] = acc[mt][nt][r];
      }
}

// ---------------- per-(s,head) RMSNorm + RoPE; Q,K -> bf16 ----------------
__global__ __launch_bounds__(256) void k_postproc(const float* __restrict__ QKV,
                                                  const float* __restrict__ qw, const float* __restrict__ kw,
                                                  u16* __restrict__ qb, u16* __restrict__ kb) {
  int s = blockIdx.x;
  int w = threadIdx.x >> 6, lane = threadIdx.x & 63;
  const float* row = QKV + (size_t)s * QKV_N;
  for (int item = w; item < 36; item += 4) {
    bool isq = item < 32;
    int h = isq ? item : item - 32;
    int base = isq ? h * 128 : 4096 + h * 128;
    float x0 = row[base + lane], x1 = row[base + 64 + lane];
    float ss = x0 * x0 + x1 * x1;
#pragma unroll
    for (int off = 1; off < 64; off <<= 1) ss += __shfl_xor(ss, off);
    float rr = rsqrtf(ss * (1.0f / 128.0f) + 1e-6f);
    const float* wn = isq ? qw : kw;
    float n0 = x0 * rr * wn[lane], n1 = x1 * rr * wn[lane + 64];
    // inv_freq = theta^(-lane/64), theta=1e6; ln(1e6)=13.815510557964274
    float inv_freq = expf(-(float)lane * (13.815510557964274f / 64.0f));
    float fr = (float)s * inv_freq;
    float sn, cs;
    sincosf(fr, &sn, &cs);
    float y0 = n0 * cs - n1 * sn;
    float y1 = n1 * cs + n0 * sn;
    if (isq) {
      size_t o = (size_t)s * QN + h * 128 + lane;
      qb[o] = f2bf(y0);
      qb[o + 64] = f2bf(y1);
    } else {
      size_t o = ((size_t)h * SEQ + s) * 128 + lane;
      kb[o] = f2bf(y0);
      kb[o + 64] = f2bf(y1);
    }
  }
}

// ---------------- V transpose: QKV fp32 [s][4608+h*128+d] -> vt bf16 [h][d][s] ----------------
__global__ __launch_bounds__(256) void k_vtrans(const float* __restrict__ QKV, u16* __restrict__ vt) {
  __shared__ float t[32][33];
  int s0 = blockIdx.x * 32, d0 = blockIdx.y * 32, h = blockIdx.z;
  int j = threadIdx.x & 31, i0 = threadIdx.x >> 5;
#pragma unroll
  for (int p = 0; p < 4; ++p) {
    int r = i0 + p * 8;
    t[r][j] = QKV[(size_t)(s0 + r) * QKV_N + 4608 + h * 128 + d0 + j];
  }
  __syncthreads();
#pragma unroll
  for (int p = 0; p < 4; ++p) {
    int r = i0 + p * 8;
    vt[((size_t)h * 128 + d0 + r) * SEQ + s0 + j] = f2bf(t[j][r]);
  }
}

// ---------------- flash attention: causal GQA, BR=64 (4 waves x 16 rows), BC=64 ----------------
__global__ __launch_bounds__(256) void k_flash(const u16* __restrict__ qb, const u16* __restrict__ kb,
                                               const u16* __restrict__ vt, u16* __restrict__ attn) {
  __shared__ u16 Ks[64 * 128];   // [t][d], chunk-swizzled
  __shared__ u16 Vts[128 * 64];  // [d][t], chunk-swizzled
  __shared__ u16 Ps[4][16 * 64]; // per-wave P tile, quad-XOR swizzled
  const int qtile = blockIdx.x, head = blockIdx.y, kvh = head >> 3;
  const int q0 = qtile * 64;
  const int tid = threadIdx.x, w = tid >> 6, lane = tid & 63, quad = lane >> 4, l15 = lane & 15;

  bf16x8 qf[4];
  {
    const u16* qrow = qb + (size_t)(q0 + w * 16 + l15) * QN + head * 128;
#pragma unroll
    for (int ks = 0; ks < 4; ++ks) qf[ks] = *(const bf16x8*)(qrow + ks * 32 + quad * 8);
  }
  f32x4 o[8];
#pragma unroll
  for (int i = 0; i < 8; ++i) o[i] = {0.f, 0.f, 0.f, 0.f};
  float m_r[4] = {-1e30f, -1e30f, -1e30f, -1e30f};
  float l_r[4] = {0.f, 0.f, 0.f, 0.f};

  const u16* kbase = kb + (size_t)kvh * SEQ * 128;
  const u16* vbase = vt + (size_t)kvh * 128 * SEQ;
  u16* pw = Ps[w];

  const int nT = qtile + 1;
  for (int ti = 0; ti < nT; ++ti) {
    const int t0 = ti * 64;
    __syncthreads();
#pragma unroll
    for (int p = 0; p < 4; ++p) {
      int ci = (w * 4 + p) * 64 + lane;
      {
        int row = ci >> 4, pc = ci & 15, gc = pc ^ (row & 15);
        gl2lds16(kbase + (size_t)(t0 + row) * 128 + gc * 8, Ks + (w * 4 + p) * 512);
      }
      {
        int d = ci >> 3, pc = ci & 7, gc = pc ^ (d & 7);
        gl2lds16(vbase + (size_t)d * SEQ + t0 + gc * 8, Vts + (w * 4 + p) * 512);
      }
    }
    __syncthreads();

    // S = Q @ K^T
    f32x4 sa[4];
#pragma unroll
    for (int nt = 0; nt < 4; ++nt) {
      f32x4 a = {0.f, 0.f, 0.f, 0.f};
#pragma unroll
      for (int ks = 0; ks < 4; ++ks) {
        int row = nt * 16 + l15;
        int col = ((ks * 4 + quad) ^ (row & 15)) * 8;
        bf16x8 kf = *(const bf16x8*)(Ks + row * 128 + col);
        a = __builtin_amdgcn_mfma_f32_16x16x32_bf16(qf[ks], kf, a, 0, 0, 0);
      }
      sa[nt] = a;
    }
    // scale + causal mask
#pragma unroll
    for (int nt = 0; nt < 4; ++nt)
#pragma unroll
      for (int r = 0; r < 4; ++r) {
        float v = sa[nt][r] * 0.08838834764831845f;
        int tcol = t0 + nt * 16 + l15;
        int qrow = q0 + w * 16 + quad * 4 + r;
        sa[nt][r] = (tcol > qrow) ? -1e30f : v;
      }
    // online softmax (row = quad*4+r, spread over 16 lanes)
    float alpha[4];
#pragma unroll
    for (int r = 0; r < 4; ++r) {
      float mx = fmaxf(fmaxf(sa[0][r], sa[1][r]), fmaxf(sa[2][r], sa[3][r]));
      mx = fmaxf(mx, __shfl_xor(mx, 1));
      mx = fmaxf(mx, __shfl_xor(mx, 2));
      mx = fmaxf(mx, __shfl_xor(mx, 4));
      mx = fmaxf(mx, __shfl_xor(mx, 8));
      float mn = fmaxf(m_r[r], mx);
      alpha[r] = __expf(m_r[r] - mn);
      m_r[r] = mn;
    }
#pragma unroll
    for (int nt = 0; nt < 4; ++nt)
#pragma unroll
      for (int r = 0; r < 4; ++r) sa[nt][r] = __expf(sa[nt][r] - m_r[r]);
#pragma unroll
    for (int r = 0; r < 4; ++r) {
      float sm = sa[0][r] + sa[1][r] + sa[2][r] + sa[3][r];
      sm += __shfl_xor(sm, 1);
      sm += __shfl_xor(sm, 2);
      sm += __shfl_xor(sm, 4);
      sm += __shfl_xor(sm, 8);
      l_r[r] = l_r[r] * alpha[r] + sm;
    }
#pragma unroll
    for (int i = 0; i < 8; ++i)
#pragma unroll
      for (int r = 0; r < 4; ++r) o[i][r] *= alpha[r];
    // P: C-layout -> LDS (bf16), quad-XOR swizzle on col bits 4-5
#pragma unroll
    for (int nt = 0; nt < 4; ++nt)
#pragma unroll
      for (int r = 0; r < 4; ++r) {
        int prow = quad * 4 + r;
        int pcol = ((nt ^ quad) << 4) + l15;
        pw[prow * 64 + pcol] = f2bf(sa[nt][r]);
      }
    asm volatile("s_waitcnt lgkmcnt(0)" ::: "memory");
    // O += P @ V
    bf16x8 pa[2];
#pragma unroll
    for (int ks2 = 0; ks2 < 2; ++ks2) {
      int col = (ks2 * 32 + quad * 8) ^ ((l15 >> 2) << 4);
      pa[ks2] = *(const bf16x8*)(pw + l15 * 64 + col);
    }
#pragma unroll
    for (int nt2 = 0; nt2 < 8; ++nt2)
#pragma unroll
      for (int ks2 = 0; ks2 < 2; ++ks2) {
        int d = nt2 * 16 + l15;
        int col = ((ks2 * 4 + quad) ^ (d & 7)) * 8;
        bf16x8 vf = *(const bf16x8*)(Vts + d * 64 + col);
        o[nt2] = __builtin_amdgcn_mfma_f32_16x16x32_bf16(pa[ks2], vf, o[nt2], 0, 0, 0);
      }
  }
  // epilogue: O / l -> attn bf16 [s][h*128+d]
#pragma unroll
  for (int nt2 = 0; nt2 < 8; ++nt2)
#pragma unroll
    for (int r = 0; r < 4; ++r) {
      size_t idx = (size_t)(q0 + w * 16 + quad * 4 + r) * QN + head * 128 + nt2 * 16 + l15;
      attn[idx] = f2bf(o[nt2][r] / l_r[r]);
    }
}

extern "C" void kernel_launch(void* const* d_in, const int* in_sizes, int n_in,
                              void* d_out, int out_size, void* d_ws, size_t ws_size,
                              hipStream_t stream) {
  const float* hidden = (const float*)d_in[0];
  const float* wq = (const float*)d_in[1];
  const float* wk = (const float*)d_in[2];
  const float* wv = (const float*)d_in[3];
  const float* wo = (const float*)d_in[4];
  const float* qnw = (const float*)d_in[5];
  const float* knw = (const float*)d_in[6];
  float* out = (float*)d_out;

  char* ws = (char*)d_ws;
  u16* hid_bf = (u16*)(ws);                  // [2048][2048]           8 MB
  u16* WT = (u16*)(ws + 8388608);            // [5120][2048]          20 MB
  u16* woT = (u16*)(ws + 29360128);          // [2048][4096]          16 MB
  float* QKV = (float*)(ws + 46137344);      // [2048][5120] fp32     40 MB
  u16* q_bf = (u16*)(ws + 88080384);         // [2048][4096]          16 MB
  u16* k_bf = (u16*)(ws + 104857600);        // [4][2048][128]         2 MB
  u16* vt = (u16*)(ws + 106954752);          // [4][128][2048]         2 MB
  u16* attn = (u16*)(ws + 109051904);        // [2048][4096]          16 MB

  k_convert<<<4096, 256, 0, stream>>>(hidden, hid_bf);
  k_transpose<<<dim3(128, 64), 256, 0, stream>>>(wq, WT, 2048, 4096);
  k_transpose<<<dim3(16, 64), 256, 0, stream>>>(wk, WT + (size_t)4096 * 2048, 2048, 512);
  k_transpose<<<dim3(16, 64), 256, 0, stream>>>(wv, WT + (size_t)4608 * 2048, 2048, 512);
  k_transpose<<<dim3(64, 128), 256, 0, stream>>>(wo, woT, 4096, 2048);
  k_gemm_bt<<<dim3(40, 16), 256, 0, stream>>>(hid_bf, WT, QKV, 2048, 5120, 2048);
  k_postproc<<<2048, 256, 0, stream>>>(QKV, qnw, knw, q_bf, k_bf);
  k_vtrans<<<dim3(64, 4, 4), 256, 0, stream>>>(QKV, vt);
  k_flash<<<dim3(32, 32), 256, 0, stream>>>(q_bf, k_bf, vt, attn);
  k_gemm_bt<<<dim3(16, 16), 256, 0, stream>>>(attn, woT, out, 2048, 2048, 4096);
}

// Round 2
// 362.126 us; speedup vs baseline: 1.3151x; 1.3151x over previous
//
#include <hip/hip_runtime.h>
#include <stdint.h>

typedef unsigned short u16;
typedef __bf16 bf16x8 __attribute__((ext_vector_type(8)));
typedef float f32x4 __attribute__((ext_vector_type(4)));

#define SEQ 2048
#define QKV_N 5120
#define QN 4096

// exp2 fast path
#if __has_builtin(__builtin_amdgcn_exp2f)
#define EXP2F __builtin_amdgcn_exp2f
#else
#define EXP2F exp2f
#endif

// q pre-scale: (1/sqrt(128)) * log2(e)  -> MFMA S = s_true*log2e
#define QSC (0.08838834764831845f * 1.4426950408889634f)
// fixed softmax max M=12 (s_true <= ||q||*||k||*scale = 11.32): p = 2^(S - 12*log2e)
#define MLOG2E 17.312340490667560f

__device__ __forceinline__ u16 f2bf(float f) {  // RNE (used for inputs)
  union { float f; unsigned u; } v; v.f = f;
  unsigned r = v.u + 0x7fffu + ((v.u >> 16) & 1u);
  return (u16)(r >> 16);
}
__device__ __forceinline__ u16 f2bf_fast(float f) {  // 2-op round-half-away
  union { float f; unsigned u; } v; v.f = f;
  return (u16)((v.u + 0x8000u) >> 16);
}

__device__ __forceinline__ void gl2lds16(const void* g, void* l) {
  __builtin_amdgcn_global_load_lds((const __attribute__((address_space(1))) void*)g,
                                   (__attribute__((address_space(3))) void*)l, 16, 0, 0);
}

// ---------------- fp32 -> bf16 convert (hidden) ----------------
__global__ __launch_bounds__(256) void k_convert(const float* __restrict__ src, u16* __restrict__ dst) {
  int i = (blockIdx.x * 256 + threadIdx.x) * 4;
  float4 v = *(const float4*)(src + i);
  ushort4 o;
  o.x = f2bf(v.x); o.y = f2bf(v.y); o.z = f2bf(v.z); o.w = f2bf(v.w);
  *(ushort4*)(dst + i) = o;
}

// ---------------- transpose + convert: src[R][C] f32 -> dst[C][R] bf16 ----------------
__global__ __launch_bounds__(256) void k_transpose(const float* __restrict__ src, u16* __restrict__ dst,
                                                   int R, int C) {
  __shared__ float t[32][33];
  int c0 = blockIdx.x * 32, r0 = blockIdx.y * 32;
  int j = threadIdx.x & 31, i0 = threadIdx.x >> 5;
#pragma unroll
  for (int p = 0; p < 4; ++p) {
    int r = i0 + p * 8;
    t[r][j] = src[(size_t)(r0 + r) * C + c0 + j];
  }
  __syncthreads();
#pragma unroll
  for (int p = 0; p < 4; ++p) {
    int r = i0 + p * 8;
    dst[(size_t)(c0 + r) * R + r0 + j] = f2bf(t[j][r]);
  }
}

// ---------------- GEMM 128x128 tile: C[M][N] = A[M][K] @ BT[N][K]^T ----------------
__global__ __launch_bounds__(256) void k_gemm_bt(const u16* __restrict__ A, const u16* __restrict__ BT,
                                                 float* __restrict__ C, int M, int N, int K) {
  __shared__ u16 As[128 * 64];
  __shared__ u16 Bs[128 * 64];
  const int tid = threadIdx.x;
  const int w = tid >> 6, lane = tid & 63, quad = lane >> 4, l15 = lane & 15;
  const int m0 = blockIdx.y * 128, n0 = blockIdx.x * 128;
  const int mw = (w & 1) * 64, nw = (w >> 1) * 64;

  f32x4 acc[4][4];
#pragma unroll
  for (int i = 0; i < 4; ++i)
#pragma unroll
    for (int j = 0; j < 4; ++j) acc[i][j] = {0.f, 0.f, 0.f, 0.f};

  const int nk = K >> 6;
  for (int kt = 0; kt < nk; ++kt) {
    const int k0 = kt << 6;
    __syncthreads();
#pragma unroll
    for (int p = 0; p < 4; ++p) {
      int ci = (w * 4 + p) * 64 + lane;
      int row = ci >> 3, pc = ci & 7, gc = pc ^ (row & 7);
      gl2lds16(A + (size_t)(m0 + row) * K + k0 + gc * 8, As + (w * 4 + p) * 512);
      gl2lds16(BT + (size_t)(n0 + row) * K + k0 + gc * 8, Bs + (w * 4 + p) * 512);
    }
    __syncthreads();
#pragma unroll
    for (int kk = 0; kk < 2; ++kk) {
      bf16x8 a[4], b[4];
#pragma unroll
      for (int mt = 0; mt < 4; ++mt) {
        int row = mw + mt * 16 + l15;
        int col = ((kk * 4 + quad) ^ (row & 7)) * 8;
        a[mt] = *(const bf16x8*)(As + row * 64 + col);
      }
#pragma unroll
      for (int nt = 0; nt < 4; ++nt) {
        int row = nw + nt * 16 + l15;
        int col = ((kk * 4 + quad) ^ (row & 7)) * 8;
        b[nt] = *(const bf16x8*)(Bs + row * 64 + col);
      }
#pragma unroll
      for (int mt = 0; mt < 4; ++mt)
#pragma unroll
        for (int nt = 0; nt < 4; ++nt)
          acc[mt][nt] = __builtin_amdgcn_mfma_f32_16x16x32_bf16(a[mt], b[nt], acc[mt][nt], 0, 0, 0);
    }
  }
#pragma unroll
  for (int mt = 0; mt < 4; ++mt)
#pragma unroll
    for (int nt = 0; nt < 4; ++nt)
#pragma unroll
      for (int r = 0; r < 4; ++r) {
        int row = m0 + mw + mt * 16 + quad * 4 + r;
        int col = n0 + nw + nt * 16 + l15;
        C[(size_t)row * N + col] = acc[mt][nt][r];
      }
}

// ---------------- GEMM 64x128 tile (higher block count for small outputs) ----------------
__global__ __launch_bounds__(256) void k_gemm_bt64(const u16* __restrict__ A, const u16* __restrict__ BT,
                                                   float* __restrict__ C, int M, int N, int K) {
  __shared__ u16 As[64 * 64];
  __shared__ u16 Bs[128 * 64];
  const int tid = threadIdx.x;
  const int w = tid >> 6, lane = tid & 63, quad = lane >> 4, l15 = lane & 15;
  const int m0 = blockIdx.y * 64, n0 = blockIdx.x * 128;
  const int nw = w * 32;

  f32x4 acc[4][2];
#pragma unroll
  for (int i = 0; i < 4; ++i)
#pragma unroll
    for (int j = 0; j < 2; ++j) acc[i][j] = {0.f, 0.f, 0.f, 0.f};

  const int nk = K >> 6;
  for (int kt = 0; kt < nk; ++kt) {
    const int k0 = kt << 6;
    __syncthreads();
#pragma unroll
    for (int p = 0; p < 2; ++p) {  // A: 512 chunks
      int ci = p * 256 + tid;
      int row = ci >> 3, gc = (ci & 7) ^ (row & 7);
      gl2lds16(A + (size_t)(m0 + row) * K + k0 + gc * 8, As + (p * 256 + w * 64) * 8);
    }
#pragma unroll
    for (int p = 0; p < 4; ++p) {  // B: 1024 chunks
      int ci = p * 256 + tid;
      int row = ci >> 3, gc = (ci & 7) ^ (row & 7);
      gl2lds16(BT + (size_t)(n0 + row) * K + k0 + gc * 8, Bs + (p * 256 + w * 64) * 8);
    }
    __syncthreads();
#pragma unroll
    for (int kk = 0; kk < 2; ++kk) {
      bf16x8 a[4], b[2];
#pragma unroll
      for (int mt = 0; mt < 4; ++mt) {
        int row = mt * 16 + l15;
        a[mt] = *(const bf16x8*)(As + row * 64 + (((kk * 4 + quad) ^ (row & 7)) * 8));
      }
#pragma unroll
      for (int nt = 0; nt < 2; ++nt) {
        int row = nw + nt * 16 + l15;
        b[nt] = *(const bf16x8*)(Bs + row * 64 + (((kk * 4 + quad) ^ (row & 7)) * 8));
      }
#pragma unroll
      for (int mt = 0; mt < 4; ++mt)
#pragma unroll
        for (int nt = 0; nt < 2; ++nt)
          acc[mt][nt] = __builtin_amdgcn_mfma_f32_16x16x32_bf16(a[mt], b[nt], acc[mt][nt], 0, 0, 0);
    }
  }
#pragma unroll
  for (int mt = 0; mt < 4; ++mt)
#pragma unroll
    for (int nt = 0; nt < 2; ++nt)
#pragma unroll
      for (int r = 0; r < 4; ++r) {
        int row = m0 + mt * 16 + quad * 4 + r;
        int col = n0 + nw + nt * 16 + l15;
        C[(size_t)row * N + col] = acc[mt][nt][r];
      }
}

// ---------------- per-(s,head) RMSNorm + RoPE; Q (pre-scaled), K -> bf16 ----------------
__global__ __launch_bounds__(256) void k_postproc(const float* __restrict__ QKV,
                                                  const float* __restrict__ qw, const float* __restrict__ kw,
                                                  u16* __restrict__ qb, u16* __restrict__ kb) {
  int s = blockIdx.x;
  int w = threadIdx.x >> 6, lane = threadIdx.x & 63;
  const float* row = QKV + (size_t)s * QKV_N;
  // hoisted: rope angle + norm weights (same for all items of this thread)
  float inv_freq = EXP2F(-(float)lane * (19.931568569324174f / 64.0f));  // 1e6^(-lane/64)
  float fr = (float)s * inv_freq;
  float sn, cs;
  __sincosf(fr, &sn, &cs);
  float qw0 = qw[lane], qw1 = qw[lane + 64];
  float kw0 = kw[lane], kw1 = kw[lane + 64];
  for (int item = w; item < 36; item += 4) {
    bool isq = item < 32;
    int h = isq ? item : item - 32;
    int base = isq ? h * 128 : 4096 + h * 128;
    float x0 = row[base + lane], x1 = row[base + 64 + lane];
    float ss = x0 * x0 + x1 * x1;
#pragma unroll
    for (int off = 1; off < 64; off <<= 1) ss += __shfl_xor(ss, off);
    float rr = rsqrtf(ss * (1.0f / 128.0f) + 1e-6f);
    float n0 = x0 * rr * (isq ? qw0 : kw0), n1 = x1 * rr * (isq ? qw1 : kw1);
    float y0 = n0 * cs - n1 * sn;
    float y1 = n1 * cs + n0 * sn;
    if (isq) {
      size_t o = (size_t)s * QN + h * 128 + lane;
      qb[o] = f2bf(y0 * QSC);
      qb[o + 64] = f2bf(y1 * QSC);
    } else {
      size_t o = ((size_t)h * SEQ + s) * 128 + lane;
      kb[o] = f2bf(y0);
      kb[o + 64] = f2bf(y1);
    }
  }
}

// ---------------- V transpose: QKV fp32 -> vt bf16 [h][d][s] ----------------
__global__ __launch_bounds__(256) void k_vtrans(const float* __restrict__ QKV, u16* __restrict__ vt) {
  __shared__ float t[32][33];
  int s0 = blockIdx.x * 32, d0 = blockIdx.y * 32, h = blockIdx.z;
  int j = threadIdx.x & 31, i0 = threadIdx.x >> 5;
#pragma unroll
  for (int p = 0; p < 4; ++p) {
    int r = i0 + p * 8;
    t[r][j] = QKV[(size_t)(s0 + r) * QKV_N + 4608 + h * 128 + d0 + j];
  }
  __syncthreads();
#pragma unroll
  for (int p = 0; p < 4; ++p) {
    int r = i0 + p * 8;
    vt[((size_t)h * 128 + d0 + r) * SEQ + s0 + j] = f2bf(t[j][r]);
  }
}

// ---------------- flash attention v2: 128-row qblocks, 32 rows/wave, fixed-max softmax ----------------
__global__ __launch_bounds__(256, 2) void k_flash(const u16* __restrict__ qb_, const u16* __restrict__ kb,
                                                  const u16* __restrict__ vt, u16* __restrict__ attn) {
  __shared__ u16 Ks[64 * 128];   // [t][d], 16-chunk XOR swizzle
  __shared__ u16 Vts[128 * 64];  // [d][t], 8-chunk XOR swizzle
  __shared__ u16 Ps[4][2048];    // per-wave 2x(16x64) P tiles, quad-XOR swizzle
  const int bx = blockIdx.x;
  const int slot = bx & 255, phase = bx >> 8;
  const int head = slot & 31;
  const int qblk = phase ? (slot >> 5) : 15 - (slot >> 5);  // pair big+small across resident blocks
  const int kvh = head >> 3;
  const int q0 = qblk * 128;
  const int tid = threadIdx.x, w = tid >> 6, lane = tid & 63, quad = lane >> 4, l15 = lane & 15;
  const int rowlo0 = q0 + w * 32, rowlo1 = rowlo0 + 16;

  bf16x8 qf[2][4];
#pragma unroll
  for (int mt = 0; mt < 2; ++mt) {
    const u16* qrow = qb_ + (size_t)(rowlo0 + mt * 16 + l15) * QN + head * 128;
#pragma unroll
    for (int ks = 0; ks < 4; ++ks) qf[mt][ks] = *(const bf16x8*)(qrow + ks * 32 + quad * 8);
  }
  f32x4 o[2][8];
#pragma unroll
  for (int mt = 0; mt < 2; ++mt)
#pragma unroll
    for (int i = 0; i < 8; ++i) o[mt][i] = {0.f, 0.f, 0.f, 0.f};
  float lr[2][4] = {{0.f, 0.f, 0.f, 0.f}, {0.f, 0.f, 0.f, 0.f}};

  const u16* kbase = kb + (size_t)kvh * SEQ * 128;
  const u16* vbase = vt + (size_t)kvh * 128 * SEQ;
  u16* pw = Ps[w];

  const int nT = 2 * qblk + 2;
  for (int ti = 0; ti < nT; ++ti) {
    const int t0 = ti * 64;
    __syncthreads();
#pragma unroll
    for (int p = 0; p < 4; ++p) {
      int ci = (w * 4 + p) * 64 + lane;
      {
        int row = ci >> 4, pc = ci & 15, gc = pc ^ (row & 15);
        gl2lds16(kbase + (size_t)(t0 + row) * 128 + gc * 8, Ks + (w * 4 + p) * 512);
      }
      {
        int d = ci >> 3, pc = ci & 7, gc = pc ^ (d & 7);
        gl2lds16(vbase + (size_t)d * SEQ + t0 + gc * 8, Vts + (w * 4 + p) * 512);
      }
    }
    __syncthreads();

    const bool a0 = t0 < rowlo0 + 16;  // a0 implies a1
    const bool a1 = t0 < rowlo1 + 16;
    if (a1) {
      // S = Q @ K^T ; K-fragments shared across both m-frags
      f32x4 sa[2][4];
#pragma unroll
      for (int mt = 0; mt < 2; ++mt)
#pragma unroll
        for (int nt = 0; nt < 4; ++nt) sa[mt][nt] = {0.f, 0.f, 0.f, 0.f};
#pragma unroll
      for (int nt = 0; nt < 4; ++nt) {
        int row = nt * 16 + l15;
#pragma unroll
        for (int ks = 0; ks < 4; ++ks) {
          bf16x8 kf = *(const bf16x8*)(Ks + row * 128 + (((ks * 4 + quad) ^ (row & 15)) * 8));
          if (a0) sa[0][nt] = __builtin_amdgcn_mfma_f32_16x16x32_bf16(qf[0][ks], kf, sa[0][nt], 0, 0, 0);
          sa[1][nt] = __builtin_amdgcn_mfma_f32_16x16x32_bf16(qf[1][ks], kf, sa[1][nt], 0, 0, 0);
        }
      }
      // fixed-max softmax: p = 2^(S - 12*log2e); mask only on diagonal tiles
#pragma unroll
      for (int mt = 0; mt < 2; ++mt) {
        if (mt == 0 && !a0) continue;
        const int rl = rowlo0 + mt * 16;
        const bool domask = (t0 + 63 > rl);
        u16* pm = pw + mt * 1024;
#pragma unroll
        for (int nt = 0; nt < 4; ++nt)
#pragma unroll
          for (int r = 0; r < 4; ++r) {
            float p = EXP2F(sa[mt][nt][r] - MLOG2E);
            if (domask) {
              int tcol = t0 + nt * 16 + l15;
              int qrow = rl + quad * 4 + r;
              p = (tcol > qrow) ? 0.f : p;
            }
            sa[mt][nt][r] = p;
            pm[(quad * 4 + r) * 64 + ((nt ^ quad) << 4) + l15] = f2bf_fast(p);
          }
#pragma unroll
        for (int r = 0; r < 4; ++r)
          lr[mt][r] += sa[mt][0][r] + sa[mt][1][r] + sa[mt][2][r] + sa[mt][3][r];
      }
      asm volatile("s_waitcnt lgkmcnt(0)" ::: "memory");
      // O += P @ V ; V-fragments shared across both m-frags
#pragma unroll
      for (int ks2 = 0; ks2 < 2; ++ks2) {
        int col = (ks2 * 32 + quad * 8) ^ ((l15 >> 2) << 4);
        bf16x8 pa0, pa1;
        if (a0) pa0 = *(const bf16x8*)(pw + l15 * 64 + col);
        pa1 = *(const bf16x8*)(pw + 1024 + l15 * 64 + col);
#pragma unroll
        for (int nt2 = 0; nt2 < 8; ++nt2) {
          int d = nt2 * 16 + l15;
          bf16x8 vf = *(const bf16x8*)(Vts + d * 64 + (((ks2 * 4 + quad) ^ (d & 7)) * 8));
          if (a0) o[0][nt2] = __builtin_amdgcn_mfma_f32_16x16x32_bf16(pa0, vf, o[0][nt2], 0, 0, 0);
          o[1][nt2] = __builtin_amdgcn_mfma_f32_16x16x32_bf16(pa1, vf, o[1][nt2], 0, 0, 0);
        }
      }
    }
  }
  // epilogue: reduce l across the 16 lanes holding each row, then O/l -> bf16
#pragma unroll
  for (int mt = 0; mt < 2; ++mt) {
    float inv[4];
#pragma unroll
    for (int r = 0; r < 4; ++r) {
      float s = lr[mt][r];
      s += __shfl_xor(s, 1);
      s += __shfl_xor(s, 2);
      s += __shfl_xor(s, 4);
      s += __shfl_xor(s, 8);
      inv[r] = 1.0f / s;
    }
#pragma unroll
    for (int nt2 = 0; nt2 < 8; ++nt2)
#pragma unroll
      for (int r = 0; r < 4; ++r) {
        size_t idx = (size_t)(rowlo0 + mt * 16 + quad * 4 + r) * QN + head * 128 + nt2 * 16 + l15;
        attn[idx] = f2bf_fast(o[mt][nt2][r] * inv[r]);
      }
  }
}

extern "C" void kernel_launch(void* const* d_in, const int* in_sizes, int n_in,
                              void* d_out, int out_size, void* d_ws, size_t ws_size,
                              hipStream_t stream) {
  const float* hidden = (const float*)d_in[0];
  const float* wq = (const float*)d_in[1];
  const float* wk = (const float*)d_in[2];
  const float* wv = (const float*)d_in[3];
  const float* wo = (const float*)d_in[4];
  const float* qnw = (const float*)d_in[5];
  const float* knw = (const float*)d_in[6];
  float* out = (float*)d_out;

  char* ws = (char*)d_ws;
  u16* hid_bf = (u16*)(ws);                  // [2048][2048]           8 MB
  u16* WT = (u16*)(ws + 8388608);            // [5120][2048]          20 MB
  u16* woT = (u16*)(ws + 29360128);          // [2048][4096]          16 MB
  float* QKV = (float*)(ws + 46137344);      // [2048][5120] fp32     40 MB
  u16* q_bf = (u16*)(ws + 88080384);         // [2048][4096]          16 MB
  u16* k_bf = (u16*)(ws + 104857600);        // [4][2048][128]         2 MB
  u16* vt = (u16*)(ws + 106954752);          // [4][128][2048]         2 MB
  u16* attn = (u16*)(ws + 109051904);        // [2048][4096]          16 MB

  k_convert<<<4096, 256, 0, stream>>>(hidden, hid_bf);
  k_transpose<<<dim3(128, 64), 256, 0, stream>>>(wq, WT, 2048, 4096);
  k_transpose<<<dim3(16, 64), 256, 0, stream>>>(wk, WT + (size_t)4096 * 2048, 2048, 512);
  k_transpose<<<dim3(16, 64), 256, 0, stream>>>(wv, WT + (size_t)4608 * 2048, 2048, 512);
  k_transpose<<<dim3(64, 128), 256, 0, stream>>>(wo, woT, 4096, 2048);
  k_gemm_bt<<<dim3(40, 16), 256, 0, stream>>>(hid_bf, WT, QKV, 2048, 5120, 2048);
  k_postproc<<<2048, 256, 0, stream>>>(QKV, qnw, knw, q_bf, k_bf);
  k_vtrans<<<dim3(64, 4, 4), 256, 0, stream>>>(QKV, vt);
  k_flash<<<512, 256, 0, stream>>>(q_bf, k_bf, vt, attn);
  k_gemm_bt64<<<dim3(16, 32), 256, 0, stream>>>(attn, woT, out, 2048, 2048, 4096);
}

// Round 3
// 340.918 us; speedup vs baseline: 1.3969x; 1.0622x over previous
//
#include <hip/hip_runtime.h>
#include <stdint.h>

typedef unsigned short u16;
typedef __bf16 bf16x8 __attribute__((ext_vector_type(8)));
typedef float f32x4 __attribute__((ext_vector_type(4)));

#define SEQ 2048
#define QKV_N 5120
#define QN 4096

#if __has_builtin(__builtin_amdgcn_exp2f)
#define EXP2F __builtin_amdgcn_exp2f
#else
#define EXP2F exp2f
#endif

// q pre-scale: (1/sqrt(128)) * log2(e)
#define QSC (0.08838834764831845f * 1.4426950408889634f)
// fixed softmax max M=12 (s_true <= 11.32): p = 2^(S - 12*log2e)
#define MLOG2E 17.312340490667560f

__device__ __forceinline__ u16 f2bf(float f) {  // RNE
  union { float f; unsigned u; } v; v.f = f;
  unsigned r = v.u + 0x7fffu + ((v.u >> 16) & 1u);
  return (u16)(r >> 16);
}
__device__ __forceinline__ u16 f2bf_fast(float f) {
  union { float f; unsigned u; } v; v.f = f;
  return (u16)((v.u + 0x8000u) >> 16);
}
__device__ __forceinline__ float bf2f(u16 b) {
  union { unsigned u; float f; } v; v.u = ((unsigned)b) << 16;
  return v.f;
}

__device__ __forceinline__ void gl2lds16(const void* g, void* l) {
  __builtin_amdgcn_global_load_lds((const __attribute__((address_space(1))) void*)g,
                                   (__attribute__((address_space(3))) void*)l, 16, 0, 0);
}

// ---------------- fp32 -> bf16 convert (hidden) ----------------
__global__ __launch_bounds__(256) void k_convert(const float* __restrict__ src, u16* __restrict__ dst) {
  int i = (blockIdx.x * 256 + threadIdx.x) * 4;
  float4 v = *(const float4*)(src + i);
  ushort4 o;
  o.x = f2bf(v.x); o.y = f2bf(v.y); o.z = f2bf(v.z); o.w = f2bf(v.w);
  *(ushort4*)(dst + i) = o;
}

// ---------------- transpose + convert: src[R][C] f32 -> dst[C][R] bf16 ----------------
__global__ __launch_bounds__(256) void k_transpose(const float* __restrict__ src, u16* __restrict__ dst,
                                                   int R, int C) {
  __shared__ float t[32][33];
  int c0 = blockIdx.x * 32, r0 = blockIdx.y * 32;
  int j = threadIdx.x & 31, i0 = threadIdx.x >> 5;
#pragma unroll
  for (int p = 0; p < 4; ++p) {
    int r = i0 + p * 8;
    t[r][j] = src[(size_t)(r0 + r) * C + c0 + j];
  }
  __syncthreads();
#pragma unroll
  for (int p = 0; p < 4; ++p) {
    int r = i0 + p * 8;
    dst[(size_t)(c0 + r) * R + r0 + j] = f2bf(t[j][r]);
  }
}

// ---------------- QKV GEMM: 128x160 tile, bf16 out ----------------
// C[M][N] = A[M][K] @ BT[N][K]^T ; grid (N/160, M/128); N=5120, K=2048
__global__ __launch_bounds__(256) void k_gemm160(const u16* __restrict__ A, const u16* __restrict__ BT,
                                                 u16* __restrict__ C, int M, int N, int K) {
  __shared__ u16 As[128 * 64];  // 16 KB
  __shared__ u16 Bs[160 * 64];  // 20 KB
  const int tid = threadIdx.x;
  const int w = tid >> 6, lane = tid & 63, quad = lane >> 4, l15 = lane & 15;
  const int m0 = blockIdx.y * 128, n0 = blockIdx.x * 160;
  const int mw = (w & 1) * 64, nw = (w >> 1) * 80;

  f32x4 acc[4][5];
#pragma unroll
  for (int i = 0; i < 4; ++i)
#pragma unroll
    for (int j = 0; j < 5; ++j) acc[i][j] = {0.f, 0.f, 0.f, 0.f};

  const int nk = K >> 6;
  for (int kt = 0; kt < nk; ++kt) {
    const int k0 = kt << 6;
    __syncthreads();
#pragma unroll
    for (int p = 0; p < 4; ++p) {  // A: 1024 chunks
      int ci = (w * 4 + p) * 64 + lane;
      int row = ci >> 3, gc = (ci & 7) ^ (row & 7);
      gl2lds16(A + (size_t)(m0 + row) * K + k0 + gc * 8, As + (w * 4 + p) * 512);
    }
#pragma unroll
    for (int p = 0; p < 5; ++p) {  // B: 1280 chunks
      int ci = (w * 5 + p) * 64 + lane;
      int row = ci >> 3, gc = (ci & 7) ^ (row & 7);
      gl2lds16(BT + (size_t)(n0 + row) * K + k0 + gc * 8, Bs + (w * 5 + p) * 512);
    }
    __syncthreads();
#pragma unroll
    for (int kk = 0; kk < 2; ++kk) {
      bf16x8 a[4], b[5];
#pragma unroll
      for (int mt = 0; mt < 4; ++mt) {
        int row = mw + mt * 16 + l15;
        a[mt] = *(const bf16x8*)(As + row * 64 + (((kk * 4 + quad) ^ (row & 7)) * 8));
      }
#pragma unroll
      for (int nt = 0; nt < 5; ++nt) {
        int row = nw + nt * 16 + l15;
        b[nt] = *(const bf16x8*)(Bs + row * 64 + (((kk * 4 + quad) ^ (row & 7)) * 8));
      }
#pragma unroll
      for (int mt = 0; mt < 4; ++mt)
#pragma unroll
        for (int nt = 0; nt < 5; ++nt)
          acc[mt][nt] = __builtin_amdgcn_mfma_f32_16x16x32_bf16(a[mt], b[nt], acc[mt][nt], 0, 0, 0);
    }
  }
#pragma unroll
  for (int mt = 0; mt < 4; ++mt)
#pragma unroll
    for (int nt = 0; nt < 5; ++nt)
#pragma unroll
      for (int r = 0; r < 4; ++r) {
        int row = m0 + mw + mt * 16 + quad * 4 + r;
        int col = n0 + nw + nt * 16 + l15;
        C[(size_t)row * N + col] = f2bf(acc[mt][nt][r]);
      }
}

// ---------------- out GEMM: 128x128 tile, split-K=2, atomic fp32 accumulate ----------------
__global__ __launch_bounds__(256) void k_gemm_sk(const u16* __restrict__ A, const u16* __restrict__ BT,
                                                 float* __restrict__ C, int M, int N, int K) {
  __shared__ u16 As[128 * 64];
  __shared__ u16 Bs[128 * 64];
  const int tid = threadIdx.x;
  const int w = tid >> 6, lane = tid & 63, quad = lane >> 4, l15 = lane & 15;
  const int m0 = blockIdx.y * 128, n0 = blockIdx.x * 128;
  const int mw = (w & 1) * 64, nw = (w >> 1) * 64;
  const int khalf = K >> 1;
  const int kbase = blockIdx.z * khalf;

  f32x4 acc[4][4];
#pragma unroll
  for (int i = 0; i < 4; ++i)
#pragma unroll
    for (int j = 0; j < 4; ++j) acc[i][j] = {0.f, 0.f, 0.f, 0.f};

  const int nk = khalf >> 6;
  for (int kt = 0; kt < nk; ++kt) {
    const int k0 = kbase + (kt << 6);
    __syncthreads();
#pragma unroll
    for (int p = 0; p < 4; ++p) {
      int ci = (w * 4 + p) * 64 + lane;
      int row = ci >> 3, gc = (ci & 7) ^ (row & 7);
      gl2lds16(A + (size_t)(m0 + row) * K + k0 + gc * 8, As + (w * 4 + p) * 512);
      gl2lds16(BT + (size_t)(n0 + row) * K + k0 + gc * 8, Bs + (w * 4 + p) * 512);
    }
    __syncthreads();
#pragma unroll
    for (int kk = 0; kk < 2; ++kk) {
      bf16x8 a[4], b[4];
#pragma unroll
      for (int mt = 0; mt < 4; ++mt) {
        int row = mw + mt * 16 + l15;
        a[mt] = *(const bf16x8*)(As + row * 64 + (((kk * 4 + quad) ^ (row & 7)) * 8));
      }
#pragma unroll
      for (int nt = 0; nt < 4; ++nt) {
        int row = nw + nt * 16 + l15;
        b[nt] = *(const bf16x8*)(Bs + row * 64 + (((kk * 4 + quad) ^ (row & 7)) * 8));
      }
#pragma unroll
      for (int mt = 0; mt < 4; ++mt)
#pragma unroll
        for (int nt = 0; nt < 4; ++nt)
          acc[mt][nt] = __builtin_amdgcn_mfma_f32_16x16x32_bf16(a[mt], b[nt], acc[mt][nt], 0, 0, 0);
    }
  }
#pragma unroll
  for (int mt = 0; mt < 4; ++mt)
#pragma unroll
    for (int nt = 0; nt < 4; ++nt)
#pragma unroll
      for (int r = 0; r < 4; ++r) {
        int row = m0 + mw + mt * 16 + quad * 4 + r;
        int col = n0 + nw + nt * 16 + l15;
        atomicAdd(&C[(size_t)row * N + col], acc[mt][nt][r]);
      }
}

// ---------------- per-(s,head) RMSNorm + RoPE on bf16 QKV; Q (pre-scaled), K -> bf16 ----------------
__global__ __launch_bounds__(256) void k_postproc(const u16* __restrict__ QKV,
                                                  const float* __restrict__ qw, const float* __restrict__ kw,
                                                  u16* __restrict__ qb, u16* __restrict__ kb) {
  int s = blockIdx.x;
  int w = threadIdx.x >> 6, lane = threadIdx.x & 63;
  const u16* row = QKV + (size_t)s * QKV_N;
  float inv_freq = EXP2F(-(float)lane * (19.931568569324174f / 64.0f));  // 1e6^(-lane/64)
  float fr = (float)s * inv_freq;
  float sn, cs;
  __sincosf(fr, &sn, &cs);
  float qw0 = qw[lane], qw1 = qw[lane + 64];
  float kw0 = kw[lane], kw1 = kw[lane + 64];
  for (int item = w; item < 36; item += 4) {
    bool isq = item < 32;
    int h = isq ? item : item - 32;
    int base = isq ? h * 128 : 4096 + h * 128;
    float x0 = bf2f(row[base + lane]), x1 = bf2f(row[base + 64 + lane]);
    float ss = x0 * x0 + x1 * x1;
#pragma unroll
    for (int off = 1; off < 64; off <<= 1) ss += __shfl_xor(ss, off);
    float rr = rsqrtf(ss * (1.0f / 128.0f) + 1e-6f);
    float n0 = x0 * rr * (isq ? qw0 : kw0), n1 = x1 * rr * (isq ? qw1 : kw1);
    float y0 = n0 * cs - n1 * sn;
    float y1 = n1 * cs + n0 * sn;
    if (isq) {
      size_t o = (size_t)s * QN + h * 128 + lane;
      qb[o] = f2bf(y0 * QSC);
      qb[o + 64] = f2bf(y1 * QSC);
    } else {
      size_t o = ((size_t)h * SEQ + s) * 128 + lane;
      kb[o] = f2bf(y0);
      kb[o + 64] = f2bf(y1);
    }
  }
}

// ---------------- V transpose: QKV bf16 -> vt bf16 [h][d][s] ----------------
__global__ __launch_bounds__(256) void k_vtrans(const u16* __restrict__ QKV, u16* __restrict__ vt) {
  __shared__ u16 t[32][34];
  int s0 = blockIdx.x * 32, d0 = blockIdx.y * 32, h = blockIdx.z;
  int j = threadIdx.x & 31, i0 = threadIdx.x >> 5;
#pragma unroll
  for (int p = 0; p < 4; ++p) {
    int r = i0 + p * 8;
    t[r][j] = QKV[(size_t)(s0 + r) * QKV_N + 4608 + h * 128 + d0 + j];
  }
  __syncthreads();
#pragma unroll
  for (int p = 0; p < 4; ++p) {
    int r = i0 + p * 8;
    vt[((size_t)h * 128 + d0 + r) * SEQ + s0 + j] = t[j][r];
  }
}

// ---------------- flash attention: 128-row qblocks, 32 rows/wave, fixed-max softmax ----------------
__global__ __launch_bounds__(256, 2) void k_flash(const u16* __restrict__ qb_, const u16* __restrict__ kb,
                                                  const u16* __restrict__ vt, u16* __restrict__ attn) {
  __shared__ u16 Ks[64 * 128];
  __shared__ u16 Vts[128 * 64];
  __shared__ u16 Ps[4][2048];
  const int bx = blockIdx.x;
  const int slot = bx & 255, phase = bx >> 8;
  const int head = slot & 31;
  const int qblk = phase ? (slot >> 5) : 15 - (slot >> 5);
  const int kvh = head >> 3;
  const int q0 = qblk * 128;
  const int tid = threadIdx.x, w = tid >> 6, lane = tid & 63, quad = lane >> 4, l15 = lane & 15;
  const int rowlo0 = q0 + w * 32, rowlo1 = rowlo0 + 16;

  bf16x8 qf[2][4];
#pragma unroll
  for (int mt = 0; mt < 2; ++mt) {
    const u16* qrow = qb_ + (size_t)(rowlo0 + mt * 16 + l15) * QN + head * 128;
#pragma unroll
    for (int ks = 0; ks < 4; ++ks) qf[mt][ks] = *(const bf16x8*)(qrow + ks * 32 + quad * 8);
  }
  f32x4 o[2][8];
#pragma unroll
  for (int mt = 0; mt < 2; ++mt)
#pragma unroll
    for (int i = 0; i < 8; ++i) o[mt][i] = {0.f, 0.f, 0.f, 0.f};
  float lr[2][4] = {{0.f, 0.f, 0.f, 0.f}, {0.f, 0.f, 0.f, 0.f}};

  const u16* kbase = kb + (size_t)kvh * SEQ * 128;
  const u16* vbase = vt + (size_t)kvh * 128 * SEQ;
  u16* pw = Ps[w];

  const int nT = 2 * qblk + 2;
  for (int ti = 0; ti < nT; ++ti) {
    const int t0 = ti * 64;
    __syncthreads();
#pragma unroll
    for (int p = 0; p < 4; ++p) {
      int ci = (w * 4 + p) * 64 + lane;
      {
        int row = ci >> 4, pc = ci & 15, gc = pc ^ (row & 15);
        gl2lds16(kbase + (size_t)(t0 + row) * 128 + gc * 8, Ks + (w * 4 + p) * 512);
      }
      {
        int d = ci >> 3, pc = ci & 7, gc = pc ^ (d & 7);
        gl2lds16(vbase + (size_t)d * SEQ + t0 + gc * 8, Vts + (w * 4 + p) * 512);
      }
    }
    __syncthreads();

    const bool a0 = t0 < rowlo0 + 16;
    const bool a1 = t0 < rowlo1 + 16;
    if (a1) {
      f32x4 sa[2][4];
#pragma unroll
      for (int mt = 0; mt < 2; ++mt)
#pragma unroll
        for (int nt = 0; nt < 4; ++nt) sa[mt][nt] = {0.f, 0.f, 0.f, 0.f};
#pragma unroll
      for (int nt = 0; nt < 4; ++nt) {
        int row = nt * 16 + l15;
#pragma unroll
        for (int ks = 0; ks < 4; ++ks) {
          bf16x8 kf = *(const bf16x8*)(Ks + row * 128 + (((ks * 4 + quad) ^ (row & 15)) * 8));
          if (a0) sa[0][nt] = __builtin_amdgcn_mfma_f32_16x16x32_bf16(qf[0][ks], kf, sa[0][nt], 0, 0, 0);
          sa[1][nt] = __builtin_amdgcn_mfma_f32_16x16x32_bf16(qf[1][ks], kf, sa[1][nt], 0, 0, 0);
        }
      }
#pragma unroll
      for (int mt = 0; mt < 2; ++mt) {
        if (mt == 0 && !a0) continue;
        const int rl = rowlo0 + mt * 16;
        const bool domask = (t0 + 63 > rl);
        u16* pm = pw + mt * 1024;
#pragma unroll
        for (int nt = 0; nt < 4; ++nt)
#pragma unroll
          for (int r = 0; r < 4; ++r) {
            float p = EXP2F(sa[mt][nt][r] - MLOG2E);
            if (domask) {
              int tcol = t0 + nt * 16 + l15;
              int qrow = rl + quad * 4 + r;
              p = (tcol > qrow) ? 0.f : p;
            }
            sa[mt][nt][r] = p;
            pm[(quad * 4 + r) * 64 + ((nt ^ quad) << 4) + l15] = f2bf_fast(p);
          }
#pragma unroll
        for (int r = 0; r < 4; ++r)
          lr[mt][r] += sa[mt][0][r] + sa[mt][1][r] + sa[mt][2][r] + sa[mt][3][r];
      }
      asm volatile("s_waitcnt lgkmcnt(0)" ::: "memory");
#pragma unroll
      for (int ks2 = 0; ks2 < 2; ++ks2) {
        int col = (ks2 * 32 + quad * 8) ^ ((l15 >> 2) << 4);
        bf16x8 pa0, pa1;
        if (a0) pa0 = *(const bf16x8*)(pw + l15 * 64 + col);
        pa1 = *(const bf16x8*)(pw + 1024 + l15 * 64 + col);
#pragma unroll
        for (int nt2 = 0; nt2 < 8; ++nt2) {
          int d = nt2 * 16 + l15;
          bf16x8 vf = *(const bf16x8*)(Vts + d * 64 + (((ks2 * 4 + quad) ^ (d & 7)) * 8));
          if (a0) o[0][nt2] = __builtin_amdgcn_mfma_f32_16x16x32_bf16(pa0, vf, o[0][nt2], 0, 0, 0);
          o[1][nt2] = __builtin_amdgcn_mfma_f32_16x16x32_bf16(pa1, vf, o[1][nt2], 0, 0, 0);
        }
      }
    }
  }
#pragma unroll
  for (int mt = 0; mt < 2; ++mt) {
    float inv[4];
#pragma unroll
    for (int r = 0; r < 4; ++r) {
      float s = lr[mt][r];
      s += __shfl_xor(s, 1);
      s += __shfl_xor(s, 2);
      s += __shfl_xor(s, 4);
      s += __shfl_xor(s, 8);
      inv[r] = 1.0f / s;
    }
#pragma unroll
    for (int nt2 = 0; nt2 < 8; ++nt2)
#pragma unroll
      for (int r = 0; r < 4; ++r) {
        size_t idx = (size_t)(rowlo0 + mt * 16 + quad * 4 + r) * QN + head * 128 + nt2 * 16 + l15;
        attn[idx] = f2bf_fast(o[mt][nt2][r] * inv[r]);
      }
  }
}

extern "C" void kernel_launch(void* const* d_in, const int* in_sizes, int n_in,
                              void* d_out, int out_size, void* d_ws, size_t ws_size,
                              hipStream_t stream) {
  const float* hidden = (const float*)d_in[0];
  const float* wq = (const float*)d_in[1];
  const float* wk = (const float*)d_in[2];
  const float* wv = (const float*)d_in[3];
  const float* wo = (const float*)d_in[4];
  const float* qnw = (const float*)d_in[5];
  const float* knw = (const float*)d_in[6];
  float* out = (float*)d_out;

  char* ws = (char*)d_ws;
  u16* hid_bf = (u16*)(ws);                  // [2048][2048]           8 MB
  u16* WT = (u16*)(ws + 8388608);            // [5120][2048]          20 MB
  u16* woT = (u16*)(ws + 29360128);          // [2048][4096]          16 MB
  u16* QKV = (u16*)(ws + 46137344);          // [2048][5120] bf16     20 MB
  u16* q_bf = (u16*)(ws + 88080384);         // [2048][4096]          16 MB
  u16* k_bf = (u16*)(ws + 104857600);        // [4][2048][128]         2 MB
  u16* vt = (u16*)(ws + 106954752);          // [4][128][2048]         2 MB
  u16* attn = (u16*)(ws + 109051904);        // [2048][4096]          16 MB

  hipMemsetAsync(d_out, 0, (size_t)2048 * 2048 * 4, stream);  // for split-K atomics
  k_convert<<<4096, 256, 0, stream>>>(hidden, hid_bf);
  k_transpose<<<dim3(128, 64), 256, 0, stream>>>(wq, WT, 2048, 4096);
  k_transpose<<<dim3(16, 64), 256, 0, stream>>>(wk, WT + (size_t)4096 * 2048, 2048, 512);
  k_transpose<<<dim3(16, 64), 256, 0, stream>>>(wv, WT + (size_t)4608 * 2048, 2048, 512);
  k_transpose<<<dim3(64, 128), 256, 0, stream>>>(wo, woT, 4096, 2048);
  k_gemm160<<<dim3(32, 16), 256, 0, stream>>>(hid_bf, WT, QKV, 2048, 5120, 2048);
  k_postproc<<<2048, 256, 0, stream>>>(QKV, qnw, knw, q_bf, k_bf);
  k_vtrans<<<dim3(64, 4, 4), 256, 0, stream>>>(QKV, vt);
  k_flash<<<512, 256, 0, stream>>>(q_bf, k_bf, vt, attn);
  k_gemm_sk<<<dim3(16, 16, 2), 256, 0, stream>>>(attn, woT, out, 2048, 2048, 4096);
}

// Round 4
// 317.505 us; speedup vs baseline: 1.4999x; 1.0737x over previous
//
#include <hip/hip_runtime.h>
#include <stdint.h>

typedef unsigned short u16;
typedef __bf16 bf16x8 __attribute__((ext_vector_type(8)));
typedef float f32x4 __attribute__((ext_vector_type(4)));

#define SEQ 2048
#define QKV_N 5120
#define QN 4096

#if __has_builtin(__builtin_amdgcn_exp2f)
#define EXP2F __builtin_amdgcn_exp2f
#else
#define EXP2F exp2f
#endif

// q pre-scale: (1/sqrt(128)) * log2(e)
#define QSC (0.08838834764831845f * 1.4426950408889634f)
// fixed softmax max M=12 (s_true <= 11.32): p = 2^(S - 12*log2e)
#define MLOG2E 17.312340490667560f

// pipeline sync primitives: raw barrier + manual waitcnt (keep prefetch in flight)
#define WAIT_VM(n) asm volatile("s_waitcnt vmcnt(" #n ")" ::: "memory")
#define WAIT_LGKM asm volatile("s_waitcnt lgkmcnt(0)" ::: "memory")
#define FENCE asm volatile("" ::: "memory")
#define BARRIER_RAW do { FENCE; __builtin_amdgcn_s_barrier(); FENCE; } while (0)

__device__ __forceinline__ u16 f2bf(float f) {  // RNE
  union { float f; unsigned u; } v; v.f = f;
  unsigned r = v.u + 0x7fffu + ((v.u >> 16) & 1u);
  return (u16)(r >> 16);
}
__device__ __forceinline__ u16 f2bf_fast(float f) {
  union { float f; unsigned u; } v; v.f = f;
  return (u16)((v.u + 0x8000u) >> 16);
}
__device__ __forceinline__ float bf2f(u16 b) {
  union { unsigned u; float f; } v; v.u = ((unsigned)b) << 16;
  return v.f;
}

__device__ __forceinline__ void gl2lds16(const void* g, void* l) {
  __builtin_amdgcn_global_load_lds((const __attribute__((address_space(1))) void*)g,
                                   (__attribute__((address_space(3))) void*)l, 16, 0, 0);
}

// ---------------- fused prep: hidden convert + 4 weight transposes (one launch) ----------------
__global__ __launch_bounds__(256) void k_prep(const float* __restrict__ hidden,
                                              const float* __restrict__ wq, const float* __restrict__ wk,
                                              const float* __restrict__ wv, const float* __restrict__ wo,
                                              u16* __restrict__ hid_bf, u16* __restrict__ WT,
                                              u16* __restrict__ woT) {
  __shared__ float t[32][33];
  int bx = blockIdx.x;
  if (bx < 4096) {  // convert hidden -> bf16
    int i = (bx * 256 + threadIdx.x) * 4;
    float4 v = *(const float4*)(hidden + i);
    ushort4 o;
    o.x = f2bf(v.x); o.y = f2bf(v.y); o.z = f2bf(v.z); o.w = f2bf(v.w);
    *(ushort4*)(hid_bf + i) = o;
    return;
  }
  const float* src; u16* dst; int R, C, cx, cy;
  if (bx < 4096 + 8192) {  // wq [2048][4096] -> WT[0..4096)
    int local = bx - 4096; src = wq; dst = WT; R = 2048; C = 4096;
    cx = local & 127; cy = local >> 7;
  } else if (bx < 4096 + 8192 + 1024) {  // wk
    int local = bx - (4096 + 8192); src = wk; dst = WT + (size_t)4096 * 2048; R = 2048; C = 512;
    cx = local & 15; cy = local >> 4;
  } else if (bx < 4096 + 8192 + 2048) {  // wv
    int local = bx - (4096 + 8192 + 1024); src = wv; dst = WT + (size_t)4608 * 2048; R = 2048; C = 512;
    cx = local & 15; cy = local >> 4;
  } else {  // wo [4096][2048] -> woT
    int local = bx - (4096 + 8192 + 2048); src = wo; dst = woT; R = 4096; C = 2048;
    cx = local & 63; cy = local >> 6;
  }
  int c0 = cx * 32, r0 = cy * 32;
  int j = threadIdx.x & 31, i0 = threadIdx.x >> 5;
#pragma unroll
  for (int p = 0; p < 4; ++p) {
    int r = i0 + p * 8;
    t[r][j] = src[(size_t)(r0 + r) * C + c0 + j];
  }
  __syncthreads();
#pragma unroll
  for (int p = 0; p < 4; ++p) {
    int r = i0 + p * 8;
    dst[(size_t)(c0 + r) * R + r0 + j] = f2bf(t[j][r]);
  }
}

// ---------------- QKV GEMM: 128x160 tile, double-buffered pipeline, bf16 out ----------------
__global__ __launch_bounds__(256) void k_gemm160(const u16* __restrict__ A, const u16* __restrict__ BT,
                                                 u16* __restrict__ C, int M, int N, int K) {
  __shared__ u16 As[2][128 * 64];  // 32 KB
  __shared__ u16 Bs[2][160 * 64];  // 40 KB
  const int tid = threadIdx.x;
  const int w = tid >> 6, lane = tid & 63, quad = lane >> 4, l15 = lane & 15;
  const int m0 = blockIdx.y * 128, n0 = blockIdx.x * 160;
  const int mw = (w & 1) * 64, nw = (w >> 1) * 80;

  f32x4 acc[4][5];
#pragma unroll
  for (int i = 0; i < 4; ++i)
#pragma unroll
    for (int j = 0; j < 5; ++j) acc[i][j] = {0.f, 0.f, 0.f, 0.f};

  auto stage = [&](int kt, int buf) {
    const int k0 = kt << 6;
#pragma unroll
    for (int p = 0; p < 4; ++p) {  // A: 1024 chunks
      int ci = (w * 4 + p) * 64 + lane;
      int row = ci >> 3, gc = (ci & 7) ^ (row & 7);
      gl2lds16(A + (size_t)(m0 + row) * K + k0 + gc * 8, &As[buf][(w * 4 + p) * 512]);
    }
#pragma unroll
    for (int p = 0; p < 5; ++p) {  // B: 1280 chunks
      int ci = (w * 5 + p) * 64 + lane;
      int row = ci >> 3, gc = (ci & 7) ^ (row & 7);
      gl2lds16(BT + (size_t)(n0 + row) * K + k0 + gc * 8, &Bs[buf][(w * 5 + p) * 512]);
    }
  };

  const int nk = K >> 6;
  stage(0, 0);
  for (int kt = 0; kt < nk; ++kt) {
    WAIT_LGKM;
    BARRIER_RAW;  // everyone done reading buf[(kt+1)&1] (iter kt-1)
    if (kt + 1 < nk) {
      stage(kt + 1, (kt + 1) & 1);
      WAIT_VM(9);  // stage(kt)'s 9 loads done; stage(kt+1) stays in flight
    } else {
      WAIT_VM(0);
    }
    BARRIER_RAW;
    const u16* Ac = As[kt & 1];
    const u16* Bc = Bs[kt & 1];
#pragma unroll
    for (int kk = 0; kk < 2; ++kk) {
      bf16x8 a[4], b[5];
#pragma unroll
      for (int mt = 0; mt < 4; ++mt) {
        int row = mw + mt * 16 + l15;
        a[mt] = *(const bf16x8*)(Ac + row * 64 + (((kk * 4 + quad) ^ (row & 7)) * 8));
      }
#pragma unroll
      for (int nt = 0; nt < 5; ++nt) {
        int row = nw + nt * 16 + l15;
        b[nt] = *(const bf16x8*)(Bc + row * 64 + (((kk * 4 + quad) ^ (row & 7)) * 8));
      }
#pragma unroll
      for (int mt = 0; mt < 4; ++mt)
#pragma unroll
        for (int nt = 0; nt < 5; ++nt)
          acc[mt][nt] = __builtin_amdgcn_mfma_f32_16x16x32_bf16(a[mt], b[nt], acc[mt][nt], 0, 0, 0);
    }
  }
#pragma unroll
  for (int mt = 0; mt < 4; ++mt)
#pragma unroll
    for (int nt = 0; nt < 5; ++nt)
#pragma unroll
      for (int r = 0; r < 4; ++r) {
        int row = m0 + mw + mt * 16 + quad * 4 + r;
        int col = n0 + nw + nt * 16 + l15;
        C[(size_t)row * N + col] = f2bf(acc[mt][nt][r]);
      }
}

// ---------------- out GEMM: 128x128 tile, split-K=2, pipelined, atomic fp32 accumulate ----------------
__global__ __launch_bounds__(256) void k_gemm_sk(const u16* __restrict__ A, const u16* __restrict__ BT,
                                                 float* __restrict__ C, int M, int N, int K) {
  __shared__ u16 As[2][128 * 64];
  __shared__ u16 Bs[2][128 * 64];
  const int tid = threadIdx.x;
  const int w = tid >> 6, lane = tid & 63, quad = lane >> 4, l15 = lane & 15;
  const int m0 = blockIdx.y * 128, n0 = blockIdx.x * 128;
  const int mw = (w & 1) * 64, nw = (w >> 1) * 64;
  const int khalf = K >> 1;
  const int kbase = blockIdx.z * khalf;

  f32x4 acc[4][4];
#pragma unroll
  for (int i = 0; i < 4; ++i)
#pragma unroll
    for (int j = 0; j < 4; ++j) acc[i][j] = {0.f, 0.f, 0.f, 0.f};

  auto stage = [&](int kt, int buf) {
    const int k0 = kbase + (kt << 6);
#pragma unroll
    for (int p = 0; p < 4; ++p) {
      int ci = (w * 4 + p) * 64 + lane;
      int row = ci >> 3, gc = (ci & 7) ^ (row & 7);
      gl2lds16(A + (size_t)(m0 + row) * K + k0 + gc * 8, &As[buf][(w * 4 + p) * 512]);
      gl2lds16(BT + (size_t)(n0 + row) * K + k0 + gc * 8, &Bs[buf][(w * 4 + p) * 512]);
    }
  };

  const int nk = khalf >> 6;
  stage(0, 0);
  for (int kt = 0; kt < nk; ++kt) {
    WAIT_LGKM;
    BARRIER_RAW;
    if (kt + 1 < nk) {
      stage(kt + 1, (kt + 1) & 1);
      WAIT_VM(8);
    } else {
      WAIT_VM(0);
    }
    BARRIER_RAW;
    const u16* Ac = As[kt & 1];
    const u16* Bc = Bs[kt & 1];
#pragma unroll
    for (int kk = 0; kk < 2; ++kk) {
      bf16x8 a[4], b[4];
#pragma unroll
      for (int mt = 0; mt < 4; ++mt) {
        int row = mw + mt * 16 + l15;
        a[mt] = *(const bf16x8*)(Ac + row * 64 + (((kk * 4 + quad) ^ (row & 7)) * 8));
      }
#pragma unroll
      for (int nt = 0; nt < 4; ++nt) {
        int row = nw + nt * 16 + l15;
        b[nt] = *(const bf16x8*)(Bc + row * 64 + (((kk * 4 + quad) ^ (row & 7)) * 8));
      }
#pragma unroll
      for (int mt = 0; mt < 4; ++mt)
#pragma unroll
        for (int nt = 0; nt < 4; ++nt)
          acc[mt][nt] = __builtin_amdgcn_mfma_f32_16x16x32_bf16(a[mt], b[nt], acc[mt][nt], 0, 0, 0);
    }
  }
#pragma unroll
  for (int mt = 0; mt < 4; ++mt)
#pragma unroll
    for (int nt = 0; nt < 4; ++nt)
#pragma unroll
      for (int r = 0; r < 4; ++r) {
        int row = m0 + mw + mt * 16 + quad * 4 + r;
        int col = n0 + nw + nt * 16 + l15;
        atomicAdd(&C[(size_t)row * N + col], acc[mt][nt][r]);
      }
}

// ---------------- fused post: RMSNorm+RoPE (blocks 0..2047) + V transpose (2048..3071) ----------------
__global__ __launch_bounds__(256) void k_post(const u16* __restrict__ QKV,
                                              const float* __restrict__ qw, const float* __restrict__ kw,
                                              u16* __restrict__ qb, u16* __restrict__ kb,
                                              u16* __restrict__ vt) {
  __shared__ u16 t[32][34];
  int bx = blockIdx.x;
  if (bx < 2048) {
    int s = bx;
    int w = threadIdx.x >> 6, lane = threadIdx.x & 63;
    const u16* row = QKV + (size_t)s * QKV_N;
    float inv_freq = EXP2F(-(float)lane * (19.931568569324174f / 64.0f));  // 1e6^(-lane/64)
    float fr = (float)s * inv_freq;
    float sn, cs;
    __sincosf(fr, &sn, &cs);
    float qw0 = qw[lane], qw1 = qw[lane + 64];
    float kw0 = kw[lane], kw1 = kw[lane + 64];
    for (int item = w; item < 36; item += 4) {
      bool isq = item < 32;
      int h = isq ? item : item - 32;
      int base = isq ? h * 128 : 4096 + h * 128;
      float x0 = bf2f(row[base + lane]), x1 = bf2f(row[base + 64 + lane]);
      float ss = x0 * x0 + x1 * x1;
#pragma unroll
      for (int off = 1; off < 64; off <<= 1) ss += __shfl_xor(ss, off);
      float rr = rsqrtf(ss * (1.0f / 128.0f) + 1e-6f);
      float n0 = x0 * rr * (isq ? qw0 : kw0), n1 = x1 * rr * (isq ? qw1 : kw1);
      float y0 = n0 * cs - n1 * sn;
      float y1 = n1 * cs + n0 * sn;
      if (isq) {
        size_t o = (size_t)s * QN + h * 128 + lane;
        qb[o] = f2bf(y0 * QSC);
        qb[o + 64] = f2bf(y1 * QSC);
      } else {
        size_t o = ((size_t)h * SEQ + s) * 128 + lane;
        kb[o] = f2bf(y0);
        kb[o + 64] = f2bf(y1);
      }
    }
    return;
  }
  // V transpose
  int local = bx - 2048;
  int s0 = (local & 63) * 32, d0 = ((local >> 6) & 3) * 32, h = local >> 8;
  int j = threadIdx.x & 31, i0 = threadIdx.x >> 5;
#pragma unroll
  for (int p = 0; p < 4; ++p) {
    int r = i0 + p * 8;
    t[r][j] = QKV[(size_t)(s0 + r) * QKV_N + 4608 + h * 128 + d0 + j];
  }
  __syncthreads();
#pragma unroll
  for (int p = 0; p < 4; ++p) {
    int r = i0 + p * 8;
    vt[((size_t)h * 128 + d0 + r) * SEQ + s0 + j] = t[j][r];
  }
}

// ---------------- flash attention: pipelined K/V staging, fixed-max softmax ----------------
__global__ __launch_bounds__(256, 2) void k_flash(const u16* __restrict__ qb_, const u16* __restrict__ kb,
                                                  const u16* __restrict__ vt, u16* __restrict__ attn) {
  __shared__ u16 Ks[2][64 * 128];   // 32 KB
  __shared__ u16 Vts[2][128 * 64];  // 32 KB
  __shared__ u16 Ps[4][2048];       // 16 KB
  const int bx = blockIdx.x;
  const int slot = bx & 255, phase = bx >> 8;
  const int head = slot & 31;
  const int qblk = phase ? (slot >> 5) : 15 - (slot >> 5);
  const int kvh = head >> 3;
  const int q0 = qblk * 128;
  const int tid = threadIdx.x, w = tid >> 6, lane = tid & 63, quad = lane >> 4, l15 = lane & 15;
  const int rowlo0 = q0 + w * 32, rowlo1 = rowlo0 + 16;

  bf16x8 qf[2][4];
#pragma unroll
  for (int mt = 0; mt < 2; ++mt) {
    const u16* qrow = qb_ + (size_t)(rowlo0 + mt * 16 + l15) * QN + head * 128;
#pragma unroll
    for (int ks = 0; ks < 4; ++ks) qf[mt][ks] = *(const bf16x8*)(qrow + ks * 32 + quad * 8);
  }
  f32x4 o[2][8];
#pragma unroll
  for (int mt = 0; mt < 2; ++mt)
#pragma unroll
    for (int i = 0; i < 8; ++i) o[mt][i] = {0.f, 0.f, 0.f, 0.f};
  float lr[2][4] = {{0.f, 0.f, 0.f, 0.f}, {0.f, 0.f, 0.f, 0.f}};

  const u16* kbase = kb + (size_t)kvh * SEQ * 128;
  const u16* vbase = vt + (size_t)kvh * 128 * SEQ;
  u16* pw = Ps[w];

  auto stage = [&](int ti, int buf) {
    const int t0 = ti * 64;
#pragma unroll
    for (int p = 0; p < 4; ++p) {
      int ci = (w * 4 + p) * 64 + lane;
      {
        int row = ci >> 4, gc = (ci & 15) ^ (row & 15);
        gl2lds16(kbase + (size_t)(t0 + row) * 128 + gc * 8, &Ks[buf][(w * 4 + p) * 512]);
      }
      {
        int d = ci >> 3, gc = (ci & 7) ^ (d & 7);
        gl2lds16(vbase + (size_t)d * SEQ + t0 + gc * 8, &Vts[buf][(w * 4 + p) * 512]);
      }
    }
  };

  const int nT = 2 * qblk + 2;
  stage(0, 0);
  for (int ti = 0; ti < nT; ++ti) {
    const int t0 = ti * 64;
    WAIT_LGKM;
    BARRIER_RAW;  // everyone done reading buf[(ti+1)&1] (iter ti-1)
    if (ti + 1 < nT) {
      stage(ti + 1, (ti + 1) & 1);
      WAIT_VM(8);  // stage(ti)'s 8 loads done; prefetch stays in flight
    } else {
      WAIT_VM(0);
    }
    BARRIER_RAW;
    const u16* Kc = Ks[ti & 1];
    const u16* Vc = Vts[ti & 1];

    const bool a0 = t0 < rowlo0 + 16;
    const bool a1 = t0 < rowlo1 + 16;
    if (a1) {
      f32x4 sa[2][4];
#pragma unroll
      for (int mt = 0; mt < 2; ++mt)
#pragma unroll
        for (int nt = 0; nt < 4; ++nt) sa[mt][nt] = {0.f, 0.f, 0.f, 0.f};
#pragma unroll
      for (int nt = 0; nt < 4; ++nt) {
        int row = nt * 16 + l15;
#pragma unroll
        for (int ks = 0; ks < 4; ++ks) {
          bf16x8 kf = *(const bf16x8*)(Kc + row * 128 + (((ks * 4 + quad) ^ (row & 15)) * 8));
          if (a0) sa[0][nt] = __builtin_amdgcn_mfma_f32_16x16x32_bf16(qf[0][ks], kf, sa[0][nt], 0, 0, 0);
          sa[1][nt] = __builtin_amdgcn_mfma_f32_16x16x32_bf16(qf[1][ks], kf, sa[1][nt], 0, 0, 0);
        }
      }
#pragma unroll
      for (int mt = 0; mt < 2; ++mt) {
        if (mt == 0 && !a0) continue;
        const int rl = rowlo0 + mt * 16;
        const bool domask = (t0 + 63 > rl);
        u16* pm = pw + mt * 1024;
#pragma unroll
        for (int nt = 0; nt < 4; ++nt)
#pragma unroll
          for (int r = 0; r < 4; ++r) {
            float p = EXP2F(sa[mt][nt][r] - MLOG2E);
            if (domask) {
              int tcol = t0 + nt * 16 + l15;
              int qrow = rl + quad * 4 + r;
              p = (tcol > qrow) ? 0.f : p;
            }
            sa[mt][nt][r] = p;
            pm[(quad * 4 + r) * 64 + ((nt ^ quad) << 4) + l15] = f2bf_fast(p);
          }
#pragma unroll
        for (int r = 0; r < 4; ++r)
          lr[mt][r] += sa[mt][0][r] + sa[mt][1][r] + sa[mt][2][r] + sa[mt][3][r];
      }
      WAIT_LGKM;  // P writes visible to own-wave reads
#pragma unroll
      for (int ks2 = 0; ks2 < 2; ++ks2) {
        int col = (ks2 * 32 + quad * 8) ^ ((l15 >> 2) << 4);
        bf16x8 pa0, pa1;
        if (a0) pa0 = *(const bf16x8*)(pw + l15 * 64 + col);
        pa1 = *(const bf16x8*)(pw + 1024 + l15 * 64 + col);
#pragma unroll
        for (int nt2 = 0; nt2 < 8; ++nt2) {
          int d = nt2 * 16 + l15;
          bf16x8 vf = *(const bf16x8*)(Vc + d * 64 + (((ks2 * 4 + quad) ^ (d & 7)) * 8));
          if (a0) o[0][nt2] = __builtin_amdgcn_mfma_f32_16x16x32_bf16(pa0, vf, o[0][nt2], 0, 0, 0);
          o[1][nt2] = __builtin_amdgcn_mfma_f32_16x16x32_bf16(pa1, vf, o[1][nt2], 0, 0, 0);
        }
      }
    }
  }
#pragma unroll
  for (int mt = 0; mt < 2; ++mt) {
    float inv[4];
#pragma unroll
    for (int r = 0; r < 4; ++r) {
      float s = lr[mt][r];
      s += __shfl_xor(s, 1);
      s += __shfl_xor(s, 2);
      s += __shfl_xor(s, 4);
      s += __shfl_xor(s, 8);
      inv[r] = 1.0f / s;
    }
#pragma unroll
    for (int nt2 = 0; nt2 < 8; ++nt2)
#pragma unroll
      for (int r = 0; r < 4; ++r) {
        size_t idx = (size_t)(rowlo0 + mt * 16 + quad * 4 + r) * QN + head * 128 + nt2 * 16 + l15;
        attn[idx] = f2bf_fast(o[mt][nt2][r] * inv[r]);
      }
  }
}

extern "C" void kernel_launch(void* const* d_in, const int* in_sizes, int n_in,
                              void* d_out, int out_size, void* d_ws, size_t ws_size,
                              hipStream_t stream) {
  const float* hidden = (const float*)d_in[0];
  const float* wq = (const float*)d_in[1];
  const float* wk = (const float*)d_in[2];
  const float* wv = (const float*)d_in[3];
  const float* wo = (const float*)d_in[4];
  const float* qnw = (const float*)d_in[5];
  const float* knw = (const float*)d_in[6];
  float* out = (float*)d_out;

  char* ws = (char*)d_ws;
  u16* hid_bf = (u16*)(ws);                  // [2048][2048]           8 MB
  u16* WT = (u16*)(ws + 8388608);            // [5120][2048]          20 MB
  u16* woT = (u16*)(ws + 29360128);          // [2048][4096]          16 MB
  u16* QKV = (u16*)(ws + 46137344);          // [2048][5120] bf16     20 MB
  u16* q_bf = (u16*)(ws + 88080384);         // [2048][4096]          16 MB
  u16* k_bf = (u16*)(ws + 104857600);        // [4][2048][128]         2 MB
  u16* vt = (u16*)(ws + 106954752);          // [4][128][2048]         2 MB
  u16* attn = (u16*)(ws + 109051904);        // [2048][4096]          16 MB

  hipMemsetAsync(d_out, 0, (size_t)2048 * 2048 * 4, stream);  // for split-K atomics
  k_prep<<<22528, 256, 0, stream>>>(hidden, wq, wk, wv, wo, hid_bf, WT, woT);
  k_gemm160<<<dim3(32, 16), 256, 0, stream>>>(hid_bf, WT, QKV, 2048, 5120, 2048);
  k_post<<<3072, 256, 0, stream>>>(QKV, qnw, knw, q_bf, k_bf, vt);
  k_flash<<<512, 256, 0, stream>>>(q_bf, k_bf, vt, attn);
  k_gemm_sk<<<dim3(16, 16, 2), 256, 0, stream>>>(attn, woT, out, 2048, 2048, 4096);
}